// Round 8
// baseline (191.144 us; speedup 1.0000x reference)
//
#include <hip/hip_runtime.h>
#include <stdint.h>

#define B_   4
#define N1_  8192
#define N2_  2048
#define CIN  512
#define COUT 256

typedef __attribute__((ext_vector_type(8))) short bf16x8;
typedef __attribute__((ext_vector_type(4))) float f32x4;

__device__ inline short f2bf(float f) {
  union { float f; unsigned u; } v; v.f = f;
  unsigned r = v.u + 0x7fffu + ((v.u >> 16) & 1u);
  return (short)(r >> 16);
}
__device__ inline float bf2f(short s) {
  union { unsigned u; float f; } v; v.u = ((unsigned)(unsigned short)s) << 16;
  return v.f;
}
__device__ inline float relu_(float x) { return fmaxf(x, 0.0f); }

// exact-fp32 sorted top-3 insert (selection must be bit-exact — round 6
// showed truncated keys flip 3rd-neighbor picks; weights tolerate rounding).
#define INS3(d, j, d0, d1, d2, i0, i1, i2)                                \
  { bool lt0 = (d) < d0, lt1 = (d) < d1, lt2 = (d) < d2;                  \
    d2 = lt1 ? d1 : (lt2 ? (d) : d2); i2 = lt1 ? i1 : (lt2 ? (j) : i2);   \
    d1 = lt0 ? d0 : (lt1 ? (d) : d1); i1 = lt0 ? i0 : (lt1 ? (j) : i1);   \
    d0 = lt0 ? (d) : d0;              i0 = lt0 ? (j) : i0; }

// async global->LDS, 16B per lane; LDS dest is wave-uniform base (+lane*16)
typedef const __attribute__((address_space(1))) unsigned int* gas_t;
typedef __attribute__((address_space(3))) unsigned int* las_t;
__device__ __forceinline__ void g2l16(const short* g, short* l) {
  __builtin_amdgcn_global_load_lds((gas_t)g, (las_t)l, 16, 0, 0);
}

// ---------------------------------------------------------------------------
// D1: knn (VALU-bound) + all prep (HBM-bound) in one dispatch — round-5
// topology (graph-replay-proven). Regions:
// [0,256) knn (128 q/block, 4 q per 8-lane group)
// [256,8448) x1->bf16, [8448,12544) x2->bf16,
// [12544,12800) W1^T, [12800,13312) W2^T, [13312,13316) stats zero.
// ---------------------------------------------------------------------------
#define KNN_B  256
#define CV1_B0 256
#define CV2_B0 8448
#define W1_B0  12544
#define W2_B0  12800
#define ST_B0  13312
#define TOT_B  13316

__global__ __launch_bounds__(256) void knn_prep(
    const float* __restrict__ p1, const float* __restrict__ p2,
    const float* __restrict__ W1, const float* __restrict__ W2,
    const float* __restrict__ x1, const float* __restrict__ x2,
    float* __restrict__ wgt, int* __restrict__ idx,
    short* __restrict__ Wt1, short* __restrict__ Wt2,
    short* __restrict__ x1b, short* __restrict__ x2b,
    float* __restrict__ stats)
{
  __shared__ float4 sp2[N2_];   // 32 KB (knn blocks only)
  const int bid = blockIdx.x;
  const int tid = threadIdx.x;

  if (bid >= KNN_B) {           // ---- prep regions ----
    if (bid < CV2_B0) {
      int i = (bid - CV1_B0) * 256 + tid;
      float4 v = ((const float4*)x1)[i];
      short4 s = { f2bf(v.x), f2bf(v.y), f2bf(v.z), f2bf(v.w) };
      ((short4*)x1b)[i] = s;
    } else if (bid < W1_B0) {
      int i = (bid - CV2_B0) * 256 + tid;
      float4 v = ((const float4*)x2)[i];
      short4 s = { f2bf(v.x), f2bf(v.y), f2bf(v.z), f2bf(v.w) };
      ((short4*)x2b)[i] = s;
    } else if (bid < W2_B0) {
      int k = (bid - W1_B0) * 256 + tid;                 // over 256*256
      Wt1[(size_t)(k & 255) * COUT + (k >> 8)] = f2bf(W1[k]);
    } else if (bid < ST_B0) {
      int k = (bid - W2_B0) * 256 + tid;                 // over 512*256
      Wt2[(size_t)(k & 255) * CIN + (k >> 8)] = f2bf(W2[k]);
    } else {
      stats[(bid - ST_B0) * 256 + tid] = 0.0f;
    }
    return;
  }

  // ---- knn: 8 lanes/group scan 256 candidates each; 4 queries/group ----
  const int b = bid & 3;
  const int qg = bid >> 2;                  // 0..63
  const float* P2 = p2 + (size_t)b * N2_ * 3;
  for (int j = tid; j < N2_; j += 256) {
    float x = P2[j * 3 + 0], y = P2[j * 3 + 1], z = P2[j * 3 + 2];
    sp2[j] = make_float4(x, y, z, x * x + y * y + z * z);
  }
  __syncthreads();

  const int sub = tid & 7;
  const int g = tid >> 3;                   // 0..31
  float nx[4], ny[4], nz[4], s1[4];
  #pragma unroll
  for (int qi = 0; qi < 4; qi++) {
    const int q = qg * 128 + qi * 32 + g;
    const float* P1 = p1 + ((size_t)b * N1_ + q) * 3;
    float x = P1[0], y = P1[1], z = P1[2];
    s1[qi] = x * x + y * y + z * z;         // re-added at weight step only
    nx[qi] = -2.0f * x; ny[qi] = -2.0f * y; nz[qi] = -2.0f * z;
  }
  float t0[4], t1[4], t2[4];
  int i0[4], i1[4], i2[4];
  #pragma unroll
  for (int qi = 0; qi < 4; qi++) {
    t0[qi] = 1e30f; t1[qi] = 1e30f; t2[qi] = 1e30f;
    i0[qi] = 0; i1[qi] = 0; i2[qi] = 0;
  }

  const float4* base = &sp2[sub];
  int jb = sub;
  for (int t = 0; t < 32; t++) {
    #pragma unroll
    for (int u = 0; u < 8; u++) {
      float4 qq = base[u * 8];              // ds_read_b128, imm offset
      const int jv = jb + u * 8;
      #pragma unroll
      for (int qi = 0; qi < 4; qi++) {
        float d = fmaf(nx[qi], qq.x, fmaf(ny[qi], qq.y, fmaf(nz[qi], qq.z, qq.w)));
        INS3(d, jv, t0[qi], t1[qi], t2[qi], i0[qi], i1[qi], i2[qi]);
      }
    }
    base += 64;
    jb += 64;
  }

  // merge the 8 partial top-3 lists within each 8-lane group
  #pragma unroll
  for (int m = 1; m < 8; m <<= 1) {
    #pragma unroll
    for (int qi = 0; qi < 4; qi++) {
      float e0 = __shfl_xor(t0[qi], m);
      float e1 = __shfl_xor(t1[qi], m);
      float e2 = __shfl_xor(t2[qi], m);
      int j0 = __shfl_xor(i0[qi], m);
      int j1 = __shfl_xor(i1[qi], m);
      int j2 = __shfl_xor(i2[qi], m);
      INS3(e0, j0, t0[qi], t1[qi], t2[qi], i0[qi], i1[qi], i2[qi]);
      INS3(e1, j1, t0[qi], t1[qi], t2[qi], i0[qi], i1[qi], i2[qi]);
      INS3(e2, j2, t0[qi], t1[qi], t2[qi], i0[qi], i1[qi], i2[qi]);
    }
  }

  if (sub == 0) {
    #pragma unroll
    for (int qi = 0; qi < 4; qi++) {
      const int q = qg * 128 + qi * 32 + g;
      float r0 = 1.0f / (t0[qi] + s1[qi] + 1e-8f);
      float r1 = 1.0f / (t1[qi] + s1[qi] + 1e-8f);
      float r2 = 1.0f / (t2[qi] + s1[qi] + 1e-8f);
      float rs = 1.0f / (r0 + r1 + r2);
      size_t o = ((size_t)b * N1_ + q) * 3;
      wgt[o + 0] = r0 * rs; wgt[o + 1] = r1 * rs; wgt[o + 2] = r2 * rs;
      idx[o + 0] = i0[qi];  idx[o + 1] = i1[qi];  idx[o + 2] = i2[qi];
    }
  }
}

// ---------------------------------------------------------------------------
// D2: both GEMMs, m97-style (identical to round 5, which passed replay).
// Y = Xb(bf16) @ Wt^T(bf16) + bias -> bf16, stats fused.
// Tile 128x128x64, global_load_lds(16B), XOR-swizzled LDS pieces.
// Blocks [0,128) = gemm2 (K=512), [128,640) = gemm1 (K=256).
// ---------------------------------------------------------------------------
#define GBM 128
#define GBN 128
#define GBK 64

__global__ __launch_bounds__(256) void gemm_fused(
    const short* __restrict__ x1b, const short* __restrict__ x2b,
    const short* __restrict__ Wt1, const short* __restrict__ Wt2,
    const float* __restrict__ bias1, const float* __restrict__ bias2,
    short* __restrict__ y1, short* __restrict__ y2,
    float* __restrict__ stats)
{
  __shared__ __align__(16) short As[GBM * GBK];   // 16 KB
  __shared__ __align__(16) short Bs[GBN * GBK];   // 16 KB

  const int bid = blockIdx.x;
  const short* X; const short* Wt; const float* bias; short* Y; float* st;
  int K, mb, nb;
  if (bid < 128) {
    X = x2b; Wt = Wt2; bias = bias2; Y = y2; st = stats + 512; K = CIN;
    mb = bid >> 1; nb = bid & 1;
  } else {
    const int t = bid - 128;
    X = x1b; Wt = Wt1; bias = bias1; Y = y1; st = stats; K = COUT;
    mb = t >> 1; nb = t & 1;
  }
  const int bm = mb * GBM;
  const int bn = nb * GBN;

  const int tid = threadIdx.x, lane = tid & 63, wave = tid >> 6;
  const int wm = (wave & 1) * 64, wn = (wave >> 1) * 64;

  f32x4 acc[4][4];
  #pragma unroll
  for (int i = 0; i < 4; i++)
    #pragma unroll
    for (int j = 0; j < 4; j++)
      #pragma unroll
      for (int e = 0; e < 4; e++) acc[i][j][e] = 0.0f;

  // staging: lane covers row chunk*8+lr, swizzled 16B piece lp = (lane&7)^lr
  const int lr = lane >> 3;
  const int lp = (lane & 7) ^ lr;
  const int lk = lp * 8;

  // fragment reads undo the swizzle
  const int fr = lane & 15;
  const int quad = lane >> 4;
  const int pA0 = ((quad ^ (fr & 7)) * 16);

  for (int k0 = 0; k0 < K; k0 += GBK) {
    #pragma unroll
    for (int i = 0; i < 4; i++) {
      const int crow = wave * 4 + i;        // chunk 0..15 (8 rows each)
      g2l16(X  + (size_t)(bm + crow * 8 + lr) * K + k0 + lk, As + crow * 512);
      g2l16(Wt + (size_t)(bn + crow * 8 + lr) * K + k0 + lk, Bs + crow * 512);
    }
    __syncthreads();

    #pragma unroll
    for (int ks = 0; ks < 2; ks++) {
      const int xo = ks * 64;
      bf16x8 af[4], bfr[4];
      #pragma unroll
      for (int i = 0; i < 4; i++) {
        af[i]  = *(const bf16x8*)((const char*)As + (wm + i * 16 + fr) * 128 + (pA0 ^ xo));
        bfr[i] = *(const bf16x8*)((const char*)Bs + (wn + i * 16 + fr) * 128 + (pA0 ^ xo));
      }
      #pragma unroll
      for (int i = 0; i < 4; i++)
        #pragma unroll
        for (int j = 0; j < 4; j++)
          acc[i][j] = __builtin_amdgcn_mfma_f32_16x16x32_bf16(af[i], bfr[j], acc[i][j], 0, 0, 0);
    }
    __syncthreads();
  }

  // epilogue: bias, bf16 write, fused per-column sum/sumsq
  const int col = fr;
  const int rq = quad * 4;
  float cs[4], cs2[4];
  #pragma unroll
  for (int ni = 0; ni < 4; ni++) { cs[ni] = 0.0f; cs2[ni] = 0.0f; }

  #pragma unroll
  for (int mi = 0; mi < 4; mi++) {
    #pragma unroll
    for (int ni = 0; ni < 4; ni++) {
      const int gm = bm + wm + mi * 16 + rq;
      const int gn = bn + wn + ni * 16 + col;
      const float bb = bias[gn];
      #pragma unroll
      for (int j = 0; j < 4; j++) {
        float v = acc[mi][ni][j] + bb;
        Y[(size_t)(gm + j) * 256 + gn] = f2bf(v);
        cs[ni] += v;
        cs2[ni] += v * v;
      }
    }
  }
  #pragma unroll
  for (int ni = 0; ni < 4; ni++) {
    cs[ni]  += __shfl_xor(cs[ni], 16);  cs[ni]  += __shfl_xor(cs[ni], 32);
    cs2[ni] += __shfl_xor(cs2[ni], 16); cs2[ni] += __shfl_xor(cs2[ni], 32);
  }
  if (lane < 16) {
    #pragma unroll
    for (int ni = 0; ni < 4; ni++) {
      const int gn = bn + wn + ni * 16 + col;
      atomicAdd(&st[gn], cs[ni]);
      atomicAdd(&st[256 + gn], cs2[ni]);
    }
  }
}

// ---------------------------------------------------------------------------
// D3: out = sum_k w_k * relu(bn2(y2[idx_k])) + relu(bn1(y1)),
// BN scale/shift computed inline from raw stats (L2-hot broadcast reads).
// ---------------------------------------------------------------------------
__global__ __launch_bounds__(256) void final_out(
    const short* __restrict__ y1, const short* __restrict__ y2,
    const float* __restrict__ stats,
    const float* __restrict__ gamma1, const float* __restrict__ beta1,
    const float* __restrict__ gamma2, const float* __restrict__ beta2,
    const float* __restrict__ wgt, const int* __restrict__ idx,
    float* __restrict__ out)
{
  const int r = blockIdx.x * 4 + (threadIdx.x >> 6);
  const int lane = threadIdx.x & 63;
  const int b = r >> 13;
  const int c = lane * 4;

  const float invM1 = 1.0f / (B_ * N1_), invM2 = 1.0f / (B_ * N2_);
  float4 su1 = *(const float4*)&stats[c];
  float4 sq1 = *(const float4*)&stats[256 + c];
  float4 su2 = *(const float4*)&stats[512 + c];
  float4 sq2 = *(const float4*)&stats[768 + c];
  float4 gm1 = *(const float4*)&gamma1[c];
  float4 bt1 = *(const float4*)&beta1[c];
  float4 gm2 = *(const float4*)&gamma2[c];
  float4 bt2 = *(const float4*)&beta2[c];

  float4 sc1, sh1, sc2, sh2;
  {
    float m, v;
    m = su1.x * invM1; v = sq1.x * invM1 - m * m; sc1.x = gm1.x * rsqrtf(v + 1e-5f); sh1.x = bt1.x - m * sc1.x;
    m = su1.y * invM1; v = sq1.y * invM1 - m * m; sc1.y = gm1.y * rsqrtf(v + 1e-5f); sh1.y = bt1.y - m * sc1.y;
    m = su1.z * invM1; v = sq1.z * invM1 - m * m; sc1.z = gm1.z * rsqrtf(v + 1e-5f); sh1.z = bt1.z - m * sc1.z;
    m = su1.w * invM1; v = sq1.w * invM1 - m * m; sc1.w = gm1.w * rsqrtf(v + 1e-5f); sh1.w = bt1.w - m * sc1.w;
    m = su2.x * invM2; v = sq2.x * invM2 - m * m; sc2.x = gm2.x * rsqrtf(v + 1e-5f); sh2.x = bt2.x - m * sc2.x;
    m = su2.y * invM2; v = sq2.y * invM2 - m * m; sc2.y = gm2.y * rsqrtf(v + 1e-5f); sh2.y = bt2.y - m * sc2.y;
    m = su2.z * invM2; v = sq2.z * invM2 - m * m; sc2.z = gm2.z * rsqrtf(v + 1e-5f); sh2.z = bt2.z - m * sc2.z;
    m = su2.w * invM2; v = sq2.w * invM2 - m * m; sc2.w = gm2.w * rsqrtf(v + 1e-5f); sh2.w = bt2.w - m * sc2.w;
  }

  const size_t wo = (size_t)r * 3;
  const float w0 = wgt[wo], w1 = wgt[wo + 1], w2 = wgt[wo + 2];
  const int i0 = idx[wo], i1 = idx[wo + 1], i2 = idx[wo + 2];

  const short* g0 = y2 + ((size_t)b * N2_ + i0) * 256;
  const short* g1 = y2 + ((size_t)b * N2_ + i1) * 256;
  const short* g2 = y2 + ((size_t)b * N2_ + i2) * 256;

  short4 s0 = *(const short4*)&g0[c];
  short4 s1 = *(const short4*)&g1[c];
  short4 s2 = *(const short4*)&g2[c];
  short4 sv = *(const short4*)&y1[(size_t)r * 256 + c];

  float4 o;
  o.x = w0 * relu_(bf2f(s0.x) * sc2.x + sh2.x) + w1 * relu_(bf2f(s1.x) * sc2.x + sh2.x)
      + w2 * relu_(bf2f(s2.x) * sc2.x + sh2.x) + relu_(bf2f(sv.x) * sc1.x + sh1.x);
  o.y = w0 * relu_(bf2f(s0.y) * sc2.y + sh2.y) + w1 * relu_(bf2f(s1.y) * sc2.y + sh2.y)
      + w2 * relu_(bf2f(s2.y) * sc2.y + sh2.y) + relu_(bf2f(sv.y) * sc1.y + sh1.y);
  o.z = w0 * relu_(bf2f(s0.z) * sc2.z + sh2.z) + w1 * relu_(bf2f(s1.z) * sc2.z + sh2.z)
      + w2 * relu_(bf2f(s2.z) * sc2.z + sh2.z) + relu_(bf2f(sv.z) * sc1.z + sh1.z);
  o.w = w0 * relu_(bf2f(s0.w) * sc2.w + sh2.w) + w1 * relu_(bf2f(s1.w) * sc2.w + sh2.w)
      + w2 * relu_(bf2f(s2.w) * sc2.w + sh2.w) + relu_(bf2f(sv.w) * sc1.w + sh1.w);

  *(float4*)&out[(size_t)r * 256 + c] = o;
}

// ---------------------------------------------------------------------------
extern "C" void kernel_launch(void* const* d_in, const int* in_sizes, int n_in,
                              void* d_out, int out_size, void* d_ws, size_t ws_size,
                              hipStream_t stream)
{
  const float* p1  = (const float*)d_in[0];
  const float* x1  = (const float*)d_in[1];
  const float* p2  = (const float*)d_in[2];
  const float* x2  = (const float*)d_in[3];
  const float* W1  = (const float*)d_in[4];
  const float* b1  = (const float*)d_in[5];
  const float* g1  = (const float*)d_in[6];
  const float* be1 = (const float*)d_in[7];
  const float* W2  = (const float*)d_in[8];
  const float* b2  = (const float*)d_in[9];
  const float* g2  = (const float*)d_in[10];
  const float* be2 = (const float*)d_in[11];
  float* out = (float*)d_out;
  char* ws = (char*)d_ws;

  // workspace layout (bytes), total ~47.3 MB
  short* y1    = (short*)(ws + 0);            // 32768*256*2 = 16777216
  short* y2    = (short*)(ws + 16777216);     // 8192*256*2  =  4194304
  short* x1b   = (short*)(ws + 20971520);     // 32768*256*2 = 16777216
  short* x2b   = (short*)(ws + 37748736);     // 8192*512*2  =  8388608
  short* Wt1   = (short*)(ws + 46137344);     // 256*256*2   =   131072
  short* Wt2   = (short*)(ws + 46268416);     // 512*256*2   =   262144
  float* stats = (float*)(ws + 46530560);     // 1024 floats
  float* wgt   = (float*)(ws + 46534656);     // 32768*3 floats
  int*   idx   = (int*)  (ws + 46927872);     // 32768*3 ints

  knn_prep<<<TOT_B, 256, 0, stream>>>(p1, p2, W1, W2, x1, x2,
                                      wgt, idx, Wt1, Wt2, x1b, x2b, stats);

  gemm_fused<<<640, 256, 0, stream>>>(x1b, x2b, Wt1, Wt2, b1, b2, y1, y2, stats);

  final_out<<<(B_ * N1_) / 4, 256, 0, stream>>>(
      y1, y2, stats, g1, be1, g2, be2, wgt, idx, out);
}

// Round 9
// 183.448 us; speedup vs baseline: 1.0420x; 1.0420x over previous
//
#include <hip/hip_runtime.h>
#include <stdint.h>

#define B_   4
#define N1_  8192
#define N2_  2048
#define CIN  512
#define COUT 256

typedef __attribute__((ext_vector_type(8))) short bf16x8;
typedef __attribute__((ext_vector_type(4))) float f32x4;

__device__ inline short f2bf(float f) {
  union { float f; unsigned u; } v; v.f = f;
  unsigned r = v.u + 0x7fffu + ((v.u >> 16) & 1u);
  return (short)(r >> 16);
}
__device__ inline float bf2f(short s) {
  union { unsigned u; float f; } v; v.u = ((unsigned)(unsigned short)s) << 16;
  return v.f;
}
__device__ inline float relu_(float x) { return fmaxf(x, 0.0f); }

// exact-fp32 sorted top-3 insert (selection must be bit-exact — round 6
// showed truncated keys flip 3rd-neighbor picks; weights tolerate rounding).
#define INS3(d, j, d0, d1, d2, i0, i1, i2)                                \
  { bool lt0 = (d) < d0, lt1 = (d) < d1, lt2 = (d) < d2;                  \
    d2 = lt1 ? d1 : (lt2 ? (d) : d2); i2 = lt1 ? i1 : (lt2 ? (j) : i2);   \
    d1 = lt0 ? d0 : (lt1 ? (d) : d1); i1 = lt0 ? i0 : (lt1 ? (j) : i1);   \
    d0 = lt0 ? (d) : d0;              i0 = lt0 ? (j) : i0; }

// async global->LDS, 16B per lane; LDS dest is wave-uniform base (+lane*16)
typedef const __attribute__((address_space(1))) unsigned int* gas_t;
typedef __attribute__((address_space(3))) unsigned int* las_t;
__device__ __forceinline__ void g2l16(const short* g, short* l) {
  __builtin_amdgcn_global_load_lds((gas_t)g, (las_t)l, 16, 0, 0);
}

// ---------------------------------------------------------------------------
// D1: knn + prep in one dispatch (round-5/8 topology, replay-proven).
// knn now 1024 blocks (4-5/CU -> 4+ waves/SIMD for latency hiding):
// 32 lanes/query-group x 4 queries, each lane scans 64 candidates.
// Prep blocks do 4x work each (shorter tail).
// Regions: [0,1024) knn, [1024,3072) x1->bf16, [3072,4096) x2->bf16,
// [4096,4160) W1^T, [4160,4288) W2^T, [4288,4289) stats zero.
// ---------------------------------------------------------------------------
#define KNN_B  1024
#define CV1_B0 1024
#define CV2_B0 3072
#define W1_B0  4096
#define W2_B0  4160
#define ST_B0  4288
#define TOT_B  4289

__global__ __launch_bounds__(256) void knn_prep(
    const float* __restrict__ p1, const float* __restrict__ p2,
    const float* __restrict__ W1, const float* __restrict__ W2,
    const float* __restrict__ x1, const float* __restrict__ x2,
    float* __restrict__ wgt, int* __restrict__ idx,
    short* __restrict__ Wt1, short* __restrict__ Wt2,
    short* __restrict__ x1b, short* __restrict__ x2b,
    float* __restrict__ stats)
{
  __shared__ float4 sp2[N2_];   // 32 KB (knn blocks only)
  const int bid = blockIdx.x;
  const int tid = threadIdx.x;

  if (bid >= KNN_B) {           // ---- prep regions (4 items/thread) ----
    if (bid < CV2_B0) {
      int i0_ = (bid - CV1_B0) * 1024 + tid;
      #pragma unroll
      for (int r = 0; r < 4; r++) {
        int i = i0_ + r * 256;
        float4 v = ((const float4*)x1)[i];
        short4 s = { f2bf(v.x), f2bf(v.y), f2bf(v.z), f2bf(v.w) };
        ((short4*)x1b)[i] = s;
      }
    } else if (bid < W1_B0) {
      int i0_ = (bid - CV2_B0) * 1024 + tid;
      #pragma unroll
      for (int r = 0; r < 4; r++) {
        int i = i0_ + r * 256;
        float4 v = ((const float4*)x2)[i];
        short4 s = { f2bf(v.x), f2bf(v.y), f2bf(v.z), f2bf(v.w) };
        ((short4*)x2b)[i] = s;
      }
    } else if (bid < W2_B0) {
      int k0_ = (bid - W1_B0) * 1024 + tid;
      #pragma unroll
      for (int r = 0; r < 4; r++) {
        int k = k0_ + r * 256;                           // over 256*256
        Wt1[(size_t)(k & 255) * COUT + (k >> 8)] = f2bf(W1[k]);
      }
    } else if (bid < ST_B0) {
      int k0_ = (bid - W2_B0) * 1024 + tid;
      #pragma unroll
      for (int r = 0; r < 4; r++) {
        int k = k0_ + r * 256;                           // over 512*256
        Wt2[(size_t)(k & 255) * CIN + (k >> 8)] = f2bf(W2[k]);
      }
    } else {
      #pragma unroll
      for (int r = 0; r < 4; r++) stats[r * 256 + tid] = 0.0f;
    }
    return;
  }

  // ---- knn: 32 lanes/group, 4 queries/group, 64 candidates/lane ----
  const int b = bid & 3;
  const int qg = bid >> 2;                  // 0..255 -> 32 queries each
  const float* P2 = p2 + (size_t)b * N2_ * 3;
  for (int j = tid; j < N2_; j += 256) {
    float x = P2[j * 3 + 0], y = P2[j * 3 + 1], z = P2[j * 3 + 2];
    sp2[j] = make_float4(x, y, z, x * x + y * y + z * z);
  }
  __syncthreads();

  const int sub = tid & 31;                 // lane within 32-lane group
  const int g32 = tid >> 5;                 // group 0..7 within block
  float nx[4], ny[4], nz[4], s1[4];
  #pragma unroll
  for (int qi = 0; qi < 4; qi++) {
    const int q = qg * 32 + qi * 8 + g32;
    const float* P1 = p1 + ((size_t)b * N1_ + q) * 3;
    float x = P1[0], y = P1[1], z = P1[2];
    s1[qi] = x * x + y * y + z * z;         // re-added at weight step only
    nx[qi] = -2.0f * x; ny[qi] = -2.0f * y; nz[qi] = -2.0f * z;
  }
  float t0[4], t1[4], t2[4];
  int i0[4], i1[4], i2[4];
  #pragma unroll
  for (int qi = 0; qi < 4; qi++) {
    t0[qi] = 1e30f; t1[qi] = 1e30f; t2[qi] = 1e30f;
    i0[qi] = 0; i1[qi] = 0; i2[qi] = 0;
  }

  const float4* base = &sp2[sub];
  int jb = sub;
  for (int t = 0; t < 8; t++) {
    #pragma unroll
    for (int u = 0; u < 8; u++) {
      float4 qq = base[u * 32];             // ds_read_b128, imm offset u*512B
      const int jv = jb + u * 32;
      #pragma unroll
      for (int qi = 0; qi < 4; qi++) {
        float d = fmaf(nx[qi], qq.x, fmaf(ny[qi], qq.y, fmaf(nz[qi], qq.z, qq.w)));
        INS3(d, jv, t0[qi], t1[qi], t2[qi], i0[qi], i1[qi], i2[qi]);
      }
    }
    base += 256;
    jb += 256;
  }

  // merge the 32 partial top-3 lists within each 32-lane group
  #pragma unroll
  for (int m = 1; m < 32; m <<= 1) {
    #pragma unroll
    for (int qi = 0; qi < 4; qi++) {
      float e0 = __shfl_xor(t0[qi], m);
      float e1 = __shfl_xor(t1[qi], m);
      float e2 = __shfl_xor(t2[qi], m);
      int j0 = __shfl_xor(i0[qi], m);
      int j1 = __shfl_xor(i1[qi], m);
      int j2 = __shfl_xor(i2[qi], m);
      INS3(e0, j0, t0[qi], t1[qi], t2[qi], i0[qi], i1[qi], i2[qi]);
      INS3(e1, j1, t0[qi], t1[qi], t2[qi], i0[qi], i1[qi], i2[qi]);
      INS3(e2, j2, t0[qi], t1[qi], t2[qi], i0[qi], i1[qi], i2[qi]);
    }
  }

  if (sub == 0) {
    #pragma unroll
    for (int qi = 0; qi < 4; qi++) {
      const int q = qg * 32 + qi * 8 + g32;
      float r0 = 1.0f / (t0[qi] + s1[qi] + 1e-8f);
      float r1 = 1.0f / (t1[qi] + s1[qi] + 1e-8f);
      float r2 = 1.0f / (t2[qi] + s1[qi] + 1e-8f);
      float rs = 1.0f / (r0 + r1 + r2);
      size_t o = ((size_t)b * N1_ + q) * 3;
      wgt[o + 0] = r0 * rs; wgt[o + 1] = r1 * rs; wgt[o + 2] = r2 * rs;
      idx[o + 0] = i0[qi];  idx[o + 1] = i1[qi];  idx[o + 2] = i2[qi];
    }
  }
}

// ---------------------------------------------------------------------------
// D2: both GEMMs, m97-style (identical to rounds 5/8, replay-proven).
// Y = Xb(bf16) @ Wt^T(bf16) + bias -> bf16, stats fused.
// Tile 128x128x64, global_load_lds(16B), XOR-swizzled LDS pieces.
// Blocks [0,128) = gemm2 (K=512), [128,640) = gemm1 (K=256).
// ---------------------------------------------------------------------------
#define GBM 128
#define GBN 128
#define GBK 64

__global__ __launch_bounds__(256) void gemm_fused(
    const short* __restrict__ x1b, const short* __restrict__ x2b,
    const short* __restrict__ Wt1, const short* __restrict__ Wt2,
    const float* __restrict__ bias1, const float* __restrict__ bias2,
    short* __restrict__ y1, short* __restrict__ y2,
    float* __restrict__ stats)
{
  __shared__ __align__(16) short As[GBM * GBK];   // 16 KB
  __shared__ __align__(16) short Bs[GBN * GBK];   // 16 KB

  const int bid = blockIdx.x;
  const short* X; const short* Wt; const float* bias; short* Y; float* st;
  int K, mb, nb;
  if (bid < 128) {
    X = x2b; Wt = Wt2; bias = bias2; Y = y2; st = stats + 512; K = CIN;
    mb = bid >> 1; nb = bid & 1;
  } else {
    const int t = bid - 128;
    X = x1b; Wt = Wt1; bias = bias1; Y = y1; st = stats; K = COUT;
    mb = t >> 1; nb = t & 1;
  }
  const int bm = mb * GBM;
  const int bn = nb * GBN;

  const int tid = threadIdx.x, lane = tid & 63, wave = tid >> 6;
  const int wm = (wave & 1) * 64, wn = (wave >> 1) * 64;

  f32x4 acc[4][4];
  #pragma unroll
  for (int i = 0; i < 4; i++)
    #pragma unroll
    for (int j = 0; j < 4; j++)
      #pragma unroll
      for (int e = 0; e < 4; e++) acc[i][j][e] = 0.0f;

  // staging: lane covers row chunk*8+lr, swizzled 16B piece lp = (lane&7)^lr
  const int lr = lane >> 3;
  const int lp = (lane & 7) ^ lr;
  const int lk = lp * 8;

  // fragment reads undo the swizzle
  const int fr = lane & 15;
  const int quad = lane >> 4;
  const int pA0 = ((quad ^ (fr & 7)) * 16);

  for (int k0 = 0; k0 < K; k0 += GBK) {
    #pragma unroll
    for (int i = 0; i < 4; i++) {
      const int crow = wave * 4 + i;        // chunk 0..15 (8 rows each)
      g2l16(X  + (size_t)(bm + crow * 8 + lr) * K + k0 + lk, As + crow * 512);
      g2l16(Wt + (size_t)(bn + crow * 8 + lr) * K + k0 + lk, Bs + crow * 512);
    }
    __syncthreads();

    #pragma unroll
    for (int ks = 0; ks < 2; ks++) {
      const int xo = ks * 64;
      bf16x8 af[4], bfr[4];
      #pragma unroll
      for (int i = 0; i < 4; i++) {
        af[i]  = *(const bf16x8*)((const char*)As + (wm + i * 16 + fr) * 128 + (pA0 ^ xo));
        bfr[i] = *(const bf16x8*)((const char*)Bs + (wn + i * 16 + fr) * 128 + (pA0 ^ xo));
      }
      #pragma unroll
      for (int i = 0; i < 4; i++)
        #pragma unroll
        for (int j = 0; j < 4; j++)
          acc[i][j] = __builtin_amdgcn_mfma_f32_16x16x32_bf16(af[i], bfr[j], acc[i][j], 0, 0, 0);
    }
    __syncthreads();
  }

  // epilogue: bias, bf16 write, fused per-column sum/sumsq
  const int col = fr;
  const int rq = quad * 4;
  float cs[4], cs2[4];
  #pragma unroll
  for (int ni = 0; ni < 4; ni++) { cs[ni] = 0.0f; cs2[ni] = 0.0f; }

  #pragma unroll
  for (int mi = 0; mi < 4; mi++) {
    #pragma unroll
    for (int ni = 0; ni < 4; ni++) {
      const int gm = bm + wm + mi * 16 + rq;
      const int gn = bn + wn + ni * 16 + col;
      const float bb = bias[gn];
      #pragma unroll
      for (int j = 0; j < 4; j++) {
        float v = acc[mi][ni][j] + bb;
        Y[(size_t)(gm + j) * 256 + gn] = f2bf(v);
        cs[ni] += v;
        cs2[ni] += v * v;
      }
    }
  }
  #pragma unroll
  for (int ni = 0; ni < 4; ni++) {
    cs[ni]  += __shfl_xor(cs[ni], 16);  cs[ni]  += __shfl_xor(cs[ni], 32);
    cs2[ni] += __shfl_xor(cs2[ni], 16); cs2[ni] += __shfl_xor(cs2[ni], 32);
  }
  if (lane < 16) {
    #pragma unroll
    for (int ni = 0; ni < 4; ni++) {
      const int gn = bn + wn + ni * 16 + col;
      atomicAdd(&st[gn], cs[ni]);
      atomicAdd(&st[256 + gn], cs2[ni]);
    }
  }
}

// ---------------------------------------------------------------------------
// D3: out = sum_k w_k * relu(bn2(y2[idx_k])) + relu(bn1(y1)),
// BN scale/shift computed inline from raw stats (L2-hot broadcast reads).
// ---------------------------------------------------------------------------
__global__ __launch_bounds__(256) void final_out(
    const short* __restrict__ y1, const short* __restrict__ y2,
    const float* __restrict__ stats,
    const float* __restrict__ gamma1, const float* __restrict__ beta1,
    const float* __restrict__ gamma2, const float* __restrict__ beta2,
    const float* __restrict__ wgt, const int* __restrict__ idx,
    float* __restrict__ out)
{
  const int r = blockIdx.x * 4 + (threadIdx.x >> 6);
  const int lane = threadIdx.x & 63;
  const int b = r >> 13;
  const int c = lane * 4;

  const float invM1 = 1.0f / (B_ * N1_), invM2 = 1.0f / (B_ * N2_);
  float4 su1 = *(const float4*)&stats[c];
  float4 sq1 = *(const float4*)&stats[256 + c];
  float4 su2 = *(const float4*)&stats[512 + c];
  float4 sq2 = *(const float4*)&stats[768 + c];
  float4 gm1 = *(const float4*)&gamma1[c];
  float4 bt1 = *(const float4*)&beta1[c];
  float4 gm2 = *(const float4*)&gamma2[c];
  float4 bt2 = *(const float4*)&beta2[c];

  float4 sc1, sh1, sc2, sh2;
  {
    float m, v;
    m = su1.x * invM1; v = sq1.x * invM1 - m * m; sc1.x = gm1.x * rsqrtf(v + 1e-5f); sh1.x = bt1.x - m * sc1.x;
    m = su1.y * invM1; v = sq1.y * invM1 - m * m; sc1.y = gm1.y * rsqrtf(v + 1e-5f); sh1.y = bt1.y - m * sc1.y;
    m = su1.z * invM1; v = sq1.z * invM1 - m * m; sc1.z = gm1.z * rsqrtf(v + 1e-5f); sh1.z = bt1.z - m * sc1.z;
    m = su1.w * invM1; v = sq1.w * invM1 - m * m; sc1.w = gm1.w * rsqrtf(v + 1e-5f); sh1.w = bt1.w - m * sc1.w;
    m = su2.x * invM2; v = sq2.x * invM2 - m * m; sc2.x = gm2.x * rsqrtf(v + 1e-5f); sh2.x = bt2.x - m * sc2.x;
    m = su2.y * invM2; v = sq2.y * invM2 - m * m; sc2.y = gm2.y * rsqrtf(v + 1e-5f); sh2.y = bt2.y - m * sc2.y;
    m = su2.z * invM2; v = sq2.z * invM2 - m * m; sc2.z = gm2.z * rsqrtf(v + 1e-5f); sh2.z = bt2.z - m * sc2.z;
    m = su2.w * invM2; v = sq2.w * invM2 - m * m; sc2.w = gm2.w * rsqrtf(v + 1e-5f); sh2.w = bt2.w - m * sc2.w;
  }

  const size_t wo = (size_t)r * 3;
  const float w0 = wgt[wo], w1 = wgt[wo + 1], w2 = wgt[wo + 2];
  const int i0 = idx[wo], i1 = idx[wo + 1], i2 = idx[wo + 2];

  const short* g0 = y2 + ((size_t)b * N2_ + i0) * 256;
  const short* g1 = y2 + ((size_t)b * N2_ + i1) * 256;
  const short* g2 = y2 + ((size_t)b * N2_ + i2) * 256;

  short4 s0 = *(const short4*)&g0[c];
  short4 s1 = *(const short4*)&g1[c];
  short4 s2 = *(const short4*)&g2[c];
  short4 sv = *(const short4*)&y1[(size_t)r * 256 + c];

  float4 o;
  o.x = w0 * relu_(bf2f(s0.x) * sc2.x + sh2.x) + w1 * relu_(bf2f(s1.x) * sc2.x + sh2.x)
      + w2 * relu_(bf2f(s2.x) * sc2.x + sh2.x) + relu_(bf2f(sv.x) * sc1.x + sh1.x);
  o.y = w0 * relu_(bf2f(s0.y) * sc2.y + sh2.y) + w1 * relu_(bf2f(s1.y) * sc2.y + sh2.y)
      + w2 * relu_(bf2f(s2.y) * sc2.y + sh2.y) + relu_(bf2f(sv.y) * sc1.y + sh1.y);
  o.z = w0 * relu_(bf2f(s0.z) * sc2.z + sh2.z) + w1 * relu_(bf2f(s1.z) * sc2.z + sh2.z)
      + w2 * relu_(bf2f(s2.z) * sc2.z + sh2.z) + relu_(bf2f(sv.z) * sc1.z + sh1.z);
  o.w = w0 * relu_(bf2f(s0.w) * sc2.w + sh2.w) + w1 * relu_(bf2f(s1.w) * sc2.w + sh2.w)
      + w2 * relu_(bf2f(s2.w) * sc2.w + sh2.w) + relu_(bf2f(sv.w) * sc1.w + sh1.w);

  *(float4*)&out[(size_t)r * 256 + c] = o;
}

// ---------------------------------------------------------------------------
extern "C" void kernel_launch(void* const* d_in, const int* in_sizes, int n_in,
                              void* d_out, int out_size, void* d_ws, size_t ws_size,
                              hipStream_t stream)
{
  const float* p1  = (const float*)d_in[0];
  const float* x1  = (const float*)d_in[1];
  const float* p2  = (const float*)d_in[2];
  const float* x2  = (const float*)d_in[3];
  const float* W1  = (const float*)d_in[4];
  const float* b1  = (const float*)d_in[5];
  const float* g1  = (const float*)d_in[6];
  const float* be1 = (const float*)d_in[7];
  const float* W2  = (const float*)d_in[8];
  const float* b2  = (const float*)d_in[9];
  const float* g2  = (const float*)d_in[10];
  const float* be2 = (const float*)d_in[11];
  float* out = (float*)d_out;
  char* ws = (char*)d_ws;

  // workspace layout (bytes), total ~47.3 MB
  short* y1    = (short*)(ws + 0);            // 32768*256*2 = 16777216
  short* y2    = (short*)(ws + 16777216);     // 8192*256*2  =  4194304
  short* x1b   = (short*)(ws + 20971520);     // 32768*256*2 = 16777216
  short* x2b   = (short*)(ws + 37748736);     // 8192*512*2  =  8388608
  short* Wt1   = (short*)(ws + 46137344);     // 256*256*2   =   131072
  short* Wt2   = (short*)(ws + 46268416);     // 512*256*2   =   262144
  float* stats = (float*)(ws + 46530560);     // 1024 floats
  float* wgt   = (float*)(ws + 46534656);     // 32768*3 floats
  int*   idx   = (int*)  (ws + 46927872);     // 32768*3 ints

  knn_prep<<<TOT_B, 256, 0, stream>>>(p1, p2, W1, W2, x1, x2,
                                      wgt, idx, Wt1, Wt2, x1b, x2b, stats);

  gemm_fused<<<640, 256, 0, stream>>>(x1b, x2b, Wt1, Wt2, b1, b2, y1, y2, stats);

  final_out<<<(B_ * N1_) / 4, 256, 0, stream>>>(
      y1, y2, stats, g1, be1, g2, be2, wgt, idx, out);
}